// Round 6
// baseline (53.713 us; speedup 1.0000x reference)
//
#include <hip/hip_runtime.h>

#define BB 16
#define HH 4
#define TT 1024
#define DD 512
#define NTAP 9
#define PF 64   // prefetch depth per buffer

// Exact, no chunking: one thread per (b,h,d) channel runs the full T=1024
// recurrence; demand = true floor 268 MB (134 read + 134 write).
// 64-deep double-buffered register prefetch: issue->use distance ~1800 cyc
// of compute > ~900 cyc HBM latency + ~1600 cyc per-CU service time, so the
// per-CU memory pipe (10 B/cyc, m13) stays saturated. Static-index circular
// history (rule #20). VGPR ~170 @ 128 thr, no spill (<450).

#define DFSMN_BLOCK(CUR, NXT, TB, STORE)                                     \
  {                                                                          \
    _Pragma("unroll")                                                        \
    for (int u = 0; u < PF; ++u) {                                           \
      const int idx = (TB) + PF + 2 + u;                                     \
      NXT[u] = (idx < TT) ? vp[(size_t)idx * DD] : 0.0f;                     \
    }                                                                        \
    _Pragma("unroll")                                                        \
    for (int u = 0; u < PF; ++u) {                                           \
      const float vt  = (u == 0) ? w0 : ((u == 1) ? w1 : CUR[(u < 2) ? 0 : (u - 2)]); \
      const float vt1 = (u == 0) ? w1 : CUR[(u < 1) ? 0 : (u - 1)];          \
      const float vt2 = CUR[u];                                              \
      float p = fmaf(vt, c0, r0 * vt1);                                      \
      p = fmaf(r1, vt2, p);                                                  \
      /* oldest tap first: p[t-1] dependency stays the LAST fma */           \
      _Pragma("unroll")                                                      \
      for (int k = NTAP - 1; k >= 0; --k)                                    \
        p = fmaf(a[k], hist[(u + 15 - k) & 15], p);                          \
      hist[u & 15] = p;                                                      \
      if (STORE) __builtin_nontemporal_store(p, &op[(size_t)((TB) + u) * DD]); \
    }                                                                        \
    w0 = CUR[PF - 2];                                                        \
    w1 = CUR[PF - 1];                                                        \
  }

__global__ __launch_bounds__(128, 1) void dfsmn_kernel(
    const float* __restrict__ v,
    const float* __restrict__ lfilt,
    const float* __restrict__ rfilt,
    float* __restrict__ out)
{
    const int d  = blockIdx.x * 128 + threadIdx.x;   // 0..511
    const int bh = blockIdx.y;                       // 0..63

    const float* __restrict__ vp = v + (size_t)bh * TT * DD + d;
    float* __restrict__ op = out + (size_t)bh * TT * DD + d;

    // per-channel coefficients
    const float c0 = 1.0f + lfilt[d];
    float a[NTAP];
#pragma unroll
    for (int k = 0; k < NTAP; ++k) a[k] = lfilt[(k + 1) * DD + d];
    const float r0 = rfilt[d];
    const float r1 = rfilt[DD + d];

    // circular history of p (hist[t & 15] = p[t]); zeros before t=0
    float hist[16];
#pragma unroll
    for (int i = 0; i < 16; ++i) hist[i] = 0.0f;

    // prologue: w0=v[0], w1=v[1], A0[u]=v[2+u]
    float A0[PF], A1[PF];
    float w0 = vp[0];
    float w1 = vp[(size_t)1 * DD];
#pragma unroll
    for (int u = 0; u < PF; ++u) {
        A0[u] = vp[(size_t)(2 + u) * DD];   // 2+63 = 65 < 1024, no guard needed
    }

    for (int tb = 0; tb < TT; tb += 2 * PF) {
        DFSMN_BLOCK(A0, A1, tb, true)
        DFSMN_BLOCK(A1, A0, tb + PF, true)
    }
}

extern "C" void kernel_launch(void* const* d_in, const int* in_sizes, int n_in,
                              void* d_out, int out_size, void* d_ws, size_t ws_size,
                              hipStream_t stream) {
    const float* v  = (const float*)d_in[0];
    const float* lf = (const float*)d_in[1];
    const float* rf = (const float*)d_in[2];
    float* out = (float*)d_out;

    dim3 grid(DD / 128, BB * HH, 1);
    dim3 block(128, 1, 1);
    dfsmn_kernel<<<grid, block, 0, stream>>>(v, lf, rf, out);
}

// Round 8
// 45.537 us; speedup vs baseline: 1.1796x; 1.1796x over previous
//
#include <hip/hip_runtime.h>
#include <stdint.h>

#define BB 16
#define HH 4
#define TT 1024
#define DD 512
#define NTAP 9
#define TS 32   // timesteps per LDS tile

// Exact kernel at the 268 MB demand floor. 1 wave/block (no barriers), 512
// blocks = 2 waves/CU. v staged via global_load_lds (in-flight loads live in
// LDS, not VGPRs -> compiler cannot shrink the pipeline, unlike R5/R6 where
// VGPR pressure made it sink loads). Double-buffered 8KB tiles; counted
// s_waitcnt vmcnt(N) (never 0 mid-loop). N is provably conservative under
// any intra-window scheduler reordering: ops-after-target >= N always.

typedef __attribute__((address_space(3))) uint32_t lds_u32;
typedef __attribute__((address_space(1))) const uint32_t glb_u32;

#define WAITV(n) asm volatile("s_waitcnt vmcnt(" #n ")" ::: "memory")
#define SB() __builtin_amdgcn_sched_barrier(0)

// Issue one tile (rows v[T0 .. T0+31] of this bh, 64-col octant) into LDS
// buffer LP (float* into __shared__). 8 x global_load_lds width 16:
// instr i: lane l -> global row T0+4i+(l>>4), col 16B-slice (l&15);
// LDS dest = LP + i*1024B + l*16B (hardware: uniform base + lane*16).
// Rows clamped to TT-1 (only matters for tile 31; zeros patched after wait).
#define ISSUE_TILE(LP, T0)                                                   \
  { _Pragma("unroll")                                                        \
    for (int i = 0; i < 8; ++i) {                                            \
      int rr_ = (T0) + 4 * i + row_off;                                      \
      rr_ = (rr_ < TT) ? rr_ : (TT - 1);                                     \
      const float* gp_ = vrow + (size_t)rr_ * DD + col_off;                  \
      __builtin_amdgcn_global_load_lds((glb_u32*)gp_,                        \
                                       (lds_u32*)((LP) + i * 256),           \
                                       16, 0, 0);                            \
    }                                                                        \
    SB(); }

// 32 recurrence steps reading tile BUFI. w0=v[t], w1=v[t+1] carried in regs;
// vt2=v[t+2] from LDS. hist circular, static indices (rule #20).
#define COMPUTE_TILE(BUFI, TB)                                               \
  { _Pragma("unroll")                                                        \
    for (int u = 0; u < TS; ++u) {                                           \
      const float vt2 = lds[BUFI][u * 64 + lane];                            \
      float p = fmaf(w0, c0, r0 * w1);                                       \
      p = fmaf(r1, vt2, p);                                                  \
      _Pragma("unroll")                                                      \
      for (int kk = NTAP - 1; kk >= 0; --kk)                                 \
        p = fmaf(a[kk], hist[(u + 15 - kk) & 15], p);                        \
      hist[u & 15] = p;                                                      \
      __builtin_nontemporal_store(p, &op[(size_t)((TB) + u) * DD]);          \
      w0 = w1; w1 = vt2;                                                     \
    } }

__global__ __launch_bounds__(64, 1) void dfsmn_kernel(
    const float* __restrict__ v,
    const float* __restrict__ lfilt,
    const float* __restrict__ rfilt,
    float* __restrict__ out)
{
    __shared__ float lds[2][TS * 64];   // 2 x 8KB tiles

    const int lane = threadIdx.x;        // 0..63
    const int dq   = blockIdx.x;         // 0..7 d-octant
    const int bh   = blockIdx.y;         // 0..63
    const int d    = dq * 64 + lane;

    const int row_off = lane >> 4;               // 0..3
    const int col_off = (lane & 15) * 4;         // float offset of 16B slice

    const float* __restrict__ vrow = v + (size_t)bh * TT * DD + dq * 64;
    float* __restrict__ op = out + (size_t)bh * TT * DD + d;

    // per-channel coefficients
    const float c0 = 1.0f + lfilt[d];
    float a[NTAP];
#pragma unroll
    for (int k = 0; k < NTAP; ++k) a[k] = lfilt[(k + 1) * DD + d];
    const float r0 = rfilt[d];
    const float r1 = rfilt[DD + d];

    float hist[16];
#pragma unroll
    for (int i = 0; i < 16; ++i) hist[i] = 0.0f;

    float w0 = vrow[lane];            // v[0]
    float w1 = vrow[DD + lane];       // v[1]

    // prologue: tile n holds v rows [32n+2 .. 32n+33]
    ISSUE_TILE(lds[0], 2);     // tile 0
    ISSUE_TILE(lds[1], 34);    // tile 1

    // phase 0: need tile0 done; ops after its loads = L1(8) -> vmcnt(8)
    WAITV(8); SB();
    COMPUTE_TILE(0, 0);
    ISSUE_TILE(lds[0], 66);    // tile 2

    // steady phases 1..28: ops after L(k) = S(k-1)(32) + L(k+1)(8) = 40
#pragma unroll 1
    for (int k = 1; k <= 27; k += 2) {
        WAITV(40); SB();
        COMPUTE_TILE(1, 32 * k);
        ISSUE_TILE(lds[1], 32 * (k + 2) + 2);
        WAITV(40); SB();
        COMPUTE_TILE(0, 32 * (k + 1));
        ISSUE_TILE(lds[0], 32 * (k + 3) + 2);
    }

    // phase 29: compute tile 29, issue tile 31 (t0=994; rows 1024,1025 clamp)
    WAITV(40); SB();
    COMPUTE_TILE(1, 928);
    ISSUE_TILE(lds[1], 994);

    // phase 30: compute tile 30 (no issue); ops after L(30) = S(29)+L(31) = 40
    WAITV(40); SB();
    COMPUTE_TILE(0, 960);

    // phase 31: ops after L(31) = S(30)(32); patch v[1024],v[1025] = 0
    WAITV(32); SB();
    lds[1][30 * 64 + lane] = 0.0f;
    lds[1][31 * 64 + lane] = 0.0f;
    COMPUTE_TILE(1, 992);
}

extern "C" void kernel_launch(void* const* d_in, const int* in_sizes, int n_in,
                              void* d_out, int out_size, void* d_ws, size_t ws_size,
                              hipStream_t stream) {
    const float* v  = (const float*)d_in[0];
    const float* lf = (const float*)d_in[1];
    const float* rf = (const float*)d_in[2];
    float* out = (float*)d_out;

    dim3 grid(DD / 64, BB * HH, 1);   // 8 octants x 64 bh = 512 blocks
    dim3 block(64, 1, 1);
    dfsmn_kernel<<<grid, block, 0, stream>>>(v, lf, rf, out);
}

// Round 10
// 45.436 us; speedup vs baseline: 1.1822x; 1.0022x over previous
//
#include <hip/hip_runtime.h>
#include <stdint.h>

#define BB 16
#define HH 4
#define TT 1024
#define DD 512
#define NTAP 9
#define TS 32   // timesteps per LDS tile

// Exact kernel at the 268 MB demand floor. 1 wave/block, 512 blocks = 2
// waves/CU. v staged via global_load_lds (in-flight loads live in LDS, not
// VGPRs -> pipeline can't be shrunk by regalloc). TRIPLE-buffered 8KB tiles
// so ISSUE(k+2) can precede COMPUTE(k) without aliasing (R9's race: with 2
// buffers, tile k+2 lands in tile k's buffer while it's being read).
// Counted s_waitcnt vmcnt(N), never 0 mid-loop: steady N=40 (newest 40 ops
// at the wait = S(k-1)(32)+L(k+1)(8); everything older incl. L(k) done).

typedef __attribute__((address_space(3))) uint32_t lds_u32;
typedef __attribute__((address_space(1))) const uint32_t glb_u32;

#define WAITV(n) asm volatile("s_waitcnt vmcnt(" #n ")" ::: "memory")
#define SB() __builtin_amdgcn_sched_barrier(0)

// Issue one tile (rows v[T0 .. T0+31] of this bh, 64-col octant) into LDS
// buffer LP. 8 x global_load_lds width 16: instr i: lane l -> global row
// T0+4i+(l>>4), 16B col-slice (l&15); LDS dest = LP + i*1024B + lane*16B.
// Rows clamped to TT-1 (only tile 31; zeros patched after its wait).
#define ISSUE_TILE(LP, T0)                                                   \
  { _Pragma("unroll")                                                        \
    for (int i = 0; i < 8; ++i) {                                            \
      int rr_ = (T0) + 4 * i + row_off;                                      \
      rr_ = (rr_ < TT) ? rr_ : (TT - 1);                                     \
      const float* gp_ = vrow + (size_t)rr_ * DD + col_off;                  \
      __builtin_amdgcn_global_load_lds((glb_u32*)gp_,                        \
                                       (lds_u32*)((LP) + i * 256),           \
                                       16, 0, 0);                            \
    }                                                                        \
    SB(); }

// 32 recurrence steps reading tile BUFI. w0=v[t], w1=v[t+1] carried in regs;
// vt2=v[t+2] from LDS. hist circular, static indices (rule #20).
#define COMPUTE_TILE(BUFI, TB)                                               \
  { _Pragma("unroll")                                                        \
    for (int u = 0; u < TS; ++u) {                                           \
      const float vt2 = lds[BUFI][u * 64 + lane];                            \
      float p = fmaf(w0, c0, r0 * w1);                                       \
      p = fmaf(r1, vt2, p);                                                  \
      _Pragma("unroll")                                                      \
      for (int kk = NTAP - 1; kk >= 0; --kk)                                 \
        p = fmaf(a[kk], hist[(u + 15 - kk) & 15], p);                        \
      hist[u & 15] = p;                                                      \
      __builtin_nontemporal_store(p, &op[(size_t)((TB) + u) * DD]);          \
      w0 = w1; w1 = vt2;                                                     \
    } }

__global__ __launch_bounds__(64, 1) void dfsmn_kernel(
    const float* __restrict__ v,
    const float* __restrict__ lfilt,
    const float* __restrict__ rfilt,
    float* __restrict__ out)
{
    __shared__ float lds[3][TS * 64];   // 3 x 8KB tiles

    const int lane = threadIdx.x;        // 0..63
    const int dq   = blockIdx.x;         // 0..7 d-octant
    const int bh   = blockIdx.y;         // 0..63
    const int d    = dq * 64 + lane;

    const int row_off = lane >> 4;               // 0..3
    const int col_off = (lane & 15) * 4;         // float offset of 16B slice

    const float* __restrict__ vrow = v + (size_t)bh * TT * DD + dq * 64;
    float* __restrict__ op = out + (size_t)bh * TT * DD + d;

    // per-channel coefficients
    const float c0 = 1.0f + lfilt[d];
    float a[NTAP];
#pragma unroll
    for (int k = 0; k < NTAP; ++k) a[k] = lfilt[(k + 1) * DD + d];
    const float r0 = rfilt[d];
    const float r1 = rfilt[DD + d];

    float hist[16];
#pragma unroll
    for (int i = 0; i < 16; ++i) hist[i] = 0.0f;

    float w0 = vrow[lane];            // v[0]
    float w1 = vrow[DD + lane];       // v[1]

    // prologue: tile n holds v rows [32n+2 .. 32n+33]; tile n -> buf n%3
    ISSUE_TILE(lds[0], 2);     // tile 0 -> buf0
    ISSUE_TILE(lds[1], 34);    // tile 1 -> buf1

    // phase 0: tile0 done when only tile1's 8 loads remain -> vmcnt(8)
    WAITV(8); SB();
    ISSUE_TILE(lds[2], 66);    // tile 2 -> buf2
    COMPUTE_TILE(0, 0);

    // steady phases 1..27 (period-3 buffer rotation):
    // phase k: WAITV(40) [newest 40 = S(k-1)+L(k+1)]; issue L(k+2); compute k
#pragma unroll 1
    for (int k = 1; k <= 25; k += 3) {
        WAITV(40); SB();
        ISSUE_TILE(lds[0], 32 * (k + 2) + 2);   // tile k+2 -> buf (k+2)%3 = 0
        COMPUTE_TILE(1, 32 * k);
        WAITV(40); SB();
        ISSUE_TILE(lds[1], 32 * (k + 3) + 2);
        COMPUTE_TILE(2, 32 * (k + 1));
        WAITV(40); SB();
        ISSUE_TILE(lds[2], 32 * (k + 4) + 2);
        COMPUTE_TILE(0, 32 * (k + 2));
    }

    // phase 28: issue L30 -> buf0, compute tile 28 (buf1)
    WAITV(40); SB();
    ISSUE_TILE(lds[0], 962);
    COMPUTE_TILE(1, 896);

    // phase 29: issue L31 -> buf1 (t0=994; rows 1024,1025 clamp), compute 29
    WAITV(40); SB();
    ISSUE_TILE(lds[1], 994);
    COMPUTE_TILE(2, 928);

    // phase 30: no issue; compute tile 30 (buf0)
    WAITV(40); SB();
    COMPUTE_TILE(0, 960);

    // phase 31: newest 32 = S(30) -> L31 done; patch v[1024],v[1025] = 0
    WAITV(32); SB();
    lds[1][30 * 64 + lane] = 0.0f;
    lds[1][31 * 64 + lane] = 0.0f;
    COMPUTE_TILE(1, 992);
}

extern "C" void kernel_launch(void* const* d_in, const int* in_sizes, int n_in,
                              void* d_out, int out_size, void* d_ws, size_t ws_size,
                              hipStream_t stream) {
    const float* v  = (const float*)d_in[0];
    const float* lf = (const float*)d_in[1];
    const float* rf = (const float*)d_in[2];
    float* out = (float*)d_out;

    dim3 grid(DD / 64, BB * HH, 1);   // 8 octants x 64 bh = 512 blocks
    dim3 block(64, 1, 1);
    dfsmn_kernel<<<grid, block, 0, stream>>>(v, lf, rf, out);
}